// Round 7
// baseline (15963.028 us; speedup 1.0000x reference)
//
#include <hip/hip_runtime.h>

#define NB 36
#define NT 60
#define NTHR 256

struct Params {
  const float *data;
  const float *W0, *b0, *W1, *b1, *W2, *b2, *Wf1, *bf1, *Wf2, *bf2;
  float *xb, *w0t, *w1t, *w2t;
  float *out0a, *out0b, *outp1, *outp2a, *outp2b, *u1s;
  float *dm0, *dm1, *dmp1, *dm2, *dmp2, *dmh1, *dmh2;
  float *acc;
  float *dmz; int dmz_n4;
};

// ---------------- prep: zero states/out, binarize+transpose input, transpose weights ----------------
__global__ void __launch_bounds__(NTHR) k_prep(Params p){
  int gt  = blockIdx.x*NTHR + threadIdx.x;
  int STR = gridDim.x*NTHR;
  if(gt < NB*11) p.acc[gt] = 0.f;
  for(int i=gt; i<p.dmz_n4; i+=STR) ((float4*)p.dmz)[i] = make_float4(0.f,0.f,0.f,0.f);
  for(int i=gt; i<NT*NB*2*32*32; i+=STR){
    int t = i / (NB*2*32*32);
    int r = i % (NB*2*32*32);
    p.xb[i] = (p.data[(size_t)r*NT + t] > 1.0f) ? 1.0f : 0.0f;
  }
  for(int i=gt; i<2*9*64; i+=STR){
    int co=i%64, rr=i/64; p.w0t[i] = p.W0[(co*2 + rr/9)*9 + rr%9];
  }
  for(int i=gt; i<64*9*128; i+=STR){
    int co=i%128, rr=i/128; p.w1t[i] = p.W1[(co*64 + rr/9)*9 + rr%9];
  }
  for(int i=gt; i<128*9*128; i+=STR){
    int co=i%128, rr=i/128; p.w2t[i] = p.W2[(co*128 + rr/9)*9 + rr%9];
  }
}

// ---------------- fused conv3x3 + LIAF (+ optional avgpool2 + LIAF) ----------------
template<int Cin,int Cout,int HW,int CO,int PX,int TY,bool POOL,int CS>
__global__ void __launch_bounds__(HW*TY)
k_conv(const float* __restrict__ x, const float* __restrict__ wt,
       const float* __restrict__ bias, float* __restrict__ dm,
       float* __restrict__ out, float* __restrict__ dmp, float* __restrict__ outp)
{
  const int NCOG = Cout/CO;
  const int TH   = PX*TY;
  const int NHG  = HW/TH;
  const int NH4  = CO/4;
  const int NTHL = HW*TY;
  int tile = blockIdx.x;
  int tid  = threadIdx.x;
  int cog = tile % NCOG;
  int hg  = (tile/NCOG) % NHG;
  int b   = tile/(NCOG*NHG);
  int w   = tid % HW;
  int ty  = tid / HW;
  int h0  = hg*TH + ty*PX;

  __shared__ __align__(16) float wl[CS*9*CO];

  float accs[PX][CO];
  #pragma unroll
  for(int p=0;p<PX;p++)
    #pragma unroll
    for(int c=0;c<CO;c++) accs[p][c]=0.f;

  for(int cs=0; cs<Cin; cs+=CS){
    __syncthreads();
    for(int j=tid; j<CS*9*CO; j+=NTHL){
      int c  = j % CO;
      int rr = j / CO;
      wl[j] = wt[(cs*9 + rr)*Cout + cog*CO + c];
    }
    __syncthreads();

    for(int lc=0; lc<CS; lc++){
      const float* xc = x + ((size_t)b*Cin + cs + lc)*HW*HW;
      float xmv[PX+2], x0v[PX+2], xpv[PX+2];
      #pragma unroll
      for(int r=0;r<PX+2;r++){
        int hh = h0 - 1 + r;
        bool hv = (hh>=0) && (hh<HW);
        const float* xr = xc + hh*HW;
        x0v[r] =  hv            ? xr[w]   : 0.f;
        xmv[r] = (hv && w>0)    ? xr[w-1] : 0.f;
        xpv[r] = (hv && w<HW-1) ? xr[w+1] : 0.f;
      }
      const float4* w4 = (const float4*)(wl + lc*9*CO);
      #pragma unroll
      for(int dh=0;dh<3;dh++){
        float4 wa[NH4], wb[NH4], wc[NH4];
        #pragma unroll
        for(int g=0;g<NH4;g++){
          wa[g] = w4[(dh*3+0)*NH4+g];
          wb[g] = w4[(dh*3+1)*NH4+g];
          wc[g] = w4[(dh*3+2)*NH4+g];
        }
        #pragma unroll
        for(int g=0;g<NH4;g++){
          const float* A  = (const float*)&wa[g];
          const float* Bp = (const float*)&wb[g];
          const float* Cp = (const float*)&wc[g];
          #pragma unroll
          for(int cc=0;cc<4;cc++){
            #pragma unroll
            for(int px=0;px<PX;px++){
              int r = dh+px;
              accs[px][g*4+cc] += A[cc]*xmv[r] + Bp[cc]*x0v[r] + Cp[cc]*xpv[r];
            }
          }
        }
      }
    }
  }

  int co0 = cog*CO;
  size_t cbase = ((size_t)b*Cout + co0)*HW*HW;
  #pragma unroll
  for(int co=0; co<CO; co++){
    float bsv = bias[co0+co];
    if constexpr(!POOL){
      #pragma unroll
      for(int px=0; px<PX; px++){
        size_t idx = cbase + (size_t)co*HW*HW + (size_t)(h0+px)*HW + w;
        float mem = dm[idx] + accs[px][co] + bsv;
        out[idx] = mem > 0.f ? mem : 0.f;
        dm[idx]  = (mem > 0.5f) ? 0.f : 0.3f*mem;
      }
    } else if constexpr(PX==2){
      float vs = 0.f;
      #pragma unroll
      for(int px=0; px<2; px++){
        size_t idx = cbase + (size_t)co*HW*HW + (size_t)(h0+px)*HW + w;
        float mem = dm[idx] + accs[px][co] + bsv;
        float o = mem > 0.f ? mem : 0.f;
        dm[idx] = (mem > 0.5f) ? 0.f : 0.3f*mem;
        vs += o;
      }
      float s = vs + __shfl_xor(vs, 1, 64);
      if((w&1)==0){
        int ph = h0>>1, pw = w>>1;
        size_t pidx = ((size_t)b*Cout + co0+co)*(HW/2)*(HW/2) + (size_t)ph*(HW/2) + pw;
        float pm = dmp[pidx] + s*0.25f;
        outp[pidx] = pm > 0.f ? pm : 0.f;
        dmp[pidx]  = (pm > 0.5f) ? 0.f : 0.3f*pm;
      }
    } else { // PX==1, HW=16: pool (h,h^1) via lane^16, (w,w^1) via lane^1
      size_t idx = cbase + (size_t)co*HW*HW + (size_t)h0*HW + w;
      float mem = dm[idx] + accs[0][co] + bsv;
      float o = mem > 0.f ? mem : 0.f;
      dm[idx] = (mem > 0.5f) ? 0.f : 0.3f*mem;
      float s = o;
      s += __shfl_xor(s, 16, 64);
      s += __shfl_xor(s, 1, 64);
      if(((ty&1)==0) && ((w&1)==0)){
        int ph = h0>>1, pw = w>>1;
        size_t pidx = ((size_t)b*Cout + co0+co)*(HW/2)*(HW/2) + (size_t)ph*(HW/2) + pw;
        float pm = dmp[pidx] + s*0.25f;
        outp[pidx] = pm > 0.f ? pm : 0.f;
        dmp[pidx]  = (pm > 0.5f) ? 0.f : 0.3f*pm;
      }
    }
  }
}

// ---------------- FC1 partial GEMM -> 32 slices ----------------
__global__ void __launch_bounds__(NTHR)
k_fc1(const float* __restrict__ X, const float* __restrict__ Wf,
      float* __restrict__ u1s){
  __shared__ __align__(16) float lds[4896];
  float* Wl = lds;
  float* Xl = lds + 32*68;
  const int tid = threadIdx.x;
  int ot = blockIdx.x & 7, ks = blockIdx.x >> 3;
  int o0 = ot*32, k0 = ks*256;
  int w_id = tid >> 6, lane = tid & 63;
  int o_l = lane & 7, bg = lane >> 3;
  float acc[4][5];
  #pragma unroll
  for(int i=0;i<4;i++)
    #pragma unroll
    for(int j=0;j<5;j++) acc[i][j]=0.f;

  for(int c=0; c<4; c++){
    int kb = k0 + c*64;
    __syncthreads();
    for(int idx=tid; idx<512; idx+=NTHR){
      int r = idx >> 4, j = idx & 15;
      *(float4*)&Wl[r*68 + j*4] = *(const float4*)&Wf[(size_t)(o0+r)*8192 + kb + j*4];
    }
    for(int idx=tid; idx<640; idx+=NTHR){
      int r = idx >> 4, j = idx & 15;
      float4 v = make_float4(0.f,0.f,0.f,0.f);
      if(r < NB) v = *(const float4*)&X[(size_t)r*8192 + kb + j*4];
      *(float4*)&Xl[r*68 + j*4] = v;
    }
    __syncthreads();
    #pragma unroll
    for(int c4=0; c4<4; c4++){
      int g = w_id*4 + c4;
      float4 wv[4], xv[5];
      #pragma unroll
      for(int oi=0;oi<4;oi++) wv[oi] = *(const float4*)&Wl[(o_l+8*oi)*68 + g*4];
      #pragma unroll
      for(int bi=0;bi<5;bi++) xv[bi] = *(const float4*)&Xl[(bg*5+bi)*68 + g*4];
      #pragma unroll
      for(int oi=0;oi<4;oi++)
        #pragma unroll
        for(int bi=0;bi<5;bi++)
          acc[oi][bi] += wv[oi].x*xv[bi].x + wv[oi].y*xv[bi].y
                       + wv[oi].z*xv[bi].z + wv[oi].w*xv[bi].w;
    }
  }
  __syncthreads();
  if(w_id > 0){
    float* r = lds + ((w_id-1)*64 + lane)*20;
    #pragma unroll
    for(int oi=0;oi<4;oi++)
      #pragma unroll
      for(int bi=0;bi<5;bi++) r[oi*5+bi] = acc[oi][bi];
  }
  __syncthreads();
  if(w_id == 0){
    #pragma unroll
    for(int wv=0;wv<3;wv++){
      float* r = lds + (wv*64 + lane)*20;
      #pragma unroll
      for(int oi=0;oi<4;oi++)
        #pragma unroll
        for(int bi=0;bi<5;bi++) acc[oi][bi] += r[oi*5+bi];
    }
    #pragma unroll
    for(int bi=0;bi<5;bi++){
      int b = bg*5 + bi;
      if(b < NB){
        #pragma unroll
        for(int oi=0;oi<4;oi++)
          u1s[((size_t)ks*NB + b)*256 + o0 + o_l + 8*oi] = acc[oi][bi];
      }
    }
  }
}

// ---------------- FC1-reduce + LIAF + FC2 + LIAF + accumulate ----------------
__global__ void __launch_bounds__(NTHR)
k_fc2(const float* __restrict__ u1s, const float* __restrict__ bf1,
      const float* __restrict__ Wf2, const float* __restrict__ bf2,
      float* __restrict__ dmh1, float* __restrict__ dmh2, float* __restrict__ acc){
  __shared__ float xs[256];
  int b = blockIdx.x;
  int o = threadIdx.x;
  float u = bf1[o];
  const float* p = u1s + (size_t)b*256 + o;
  #pragma unroll
  for(int s=0;s<32;s++) u += p[(size_t)s*NB*256];
  int idx = b*256 + o;
  float mem = dmh1[idx] + u;
  float xo = mem > 0.f ? mem : 0.f;
  dmh1[idx] = (mem > 0.5f) ? 0.f : 0.3f*mem;
  xs[o] = xo;
  __syncthreads();
  int w_id = o >> 6, lane = o & 63;
  for(int oo=w_id; oo<11; oo+=4){
    const float* wr = Wf2 + oo*256;
    float s = xs[lane]*wr[lane] + xs[lane+64]*wr[lane+64]
            + xs[lane+128]*wr[lane+128] + xs[lane+192]*wr[lane+192];
    #pragma unroll
    for(int off=32; off>0; off>>=1) s += __shfl_down(s, off, 64);
    if(lane==0){
      int i2 = b*11 + oo;
      float m2 = dmh2[i2] + s + bf2[oo];
      float ov = m2 > 0.f ? m2 : 0.f;
      dmh2[i2] = (m2 > 0.5f) ? 0.f : 0.3f*m2;
      acc[i2] += ov * (1.0f/60.0f);
    }
  }
}

// ==================== launch: 3-stream software pipeline ====================
// Critical path (primary stream A): conv1(t) -> conv2(t).  conv0 runs on sC
// under conv1(t-1..); fc1+fc2 run on sB under conv0/conv1(t+1).
// out0 and outp2 double-buffered; events order cross-stream hazards.
static hipStream_t sB = nullptr, sC = nullptr;
static hipEvent_t evFork = nullptr;
static hipEvent_t evA1[NT], evA2[NT], evB[NT], evC[NT];

extern "C" void kernel_launch(void* const* d_in, const int* in_sizes, int n_in,
                              void* d_out, int out_size, void* d_ws, size_t ws_size,
                              hipStream_t stream) {
  if(!sB){
    hipStreamCreateWithFlags(&sB, hipStreamNonBlocking);
    hipStreamCreateWithFlags(&sC, hipStreamNonBlocking);
    hipEventCreateWithFlags(&evFork, hipEventDisableTiming);
    for(int t=0;t<NT;t++){
      hipEventCreateWithFlags(&evA1[t], hipEventDisableTiming);
      hipEventCreateWithFlags(&evA2[t], hipEventDisableTiming);
      hipEventCreateWithFlags(&evB[t],  hipEventDisableTiming);
      hipEventCreateWithFlags(&evC[t],  hipEventDisableTiming);
    }
  }

  Params p;
  p.data = (const float*)d_in[0];
  p.W0  = (const float*)d_in[2];  p.b0  = (const float*)d_in[3];
  p.W1  = (const float*)d_in[4];  p.b1  = (const float*)d_in[5];
  p.W2  = (const float*)d_in[6];  p.b2  = (const float*)d_in[7];
  p.Wf1 = (const float*)d_in[8];  p.bf1 = (const float*)d_in[9];
  p.Wf2 = (const float*)d_in[10]; p.bf2 = (const float*)d_in[11];
  p.acc = (float*)d_out;

  float* ws = (float*)d_ws;
  const size_t S_XB   = (size_t)NT*NB*2*32*32;
  const size_t S_W0T  = 2*9*64;
  const size_t S_W1T  = 64*9*128;
  const size_t S_W2T  = 128*9*128;
  const size_t S_OUT0 = (size_t)NB*64*32*32;
  const size_t S_DM1  = (size_t)NB*128*32*32;
  const size_t S_OP1  = (size_t)NB*128*16*16;
  const size_t S_OP2  = (size_t)NB*128*8*8;
  const size_t S_OH1  = (size_t)NB*256;
  const size_t S_U1S  = (size_t)32*NB*256;

  p.xb     = ws;  ws += S_XB;
  p.w0t    = ws;  ws += S_W0T;
  p.w1t    = ws;  ws += S_W1T;
  p.w2t    = ws;  ws += S_W2T;
  p.out0a  = ws;  ws += S_OUT0;
  p.out0b  = ws;  ws += S_OUT0;
  p.outp1  = ws;  ws += S_OP1;
  p.outp2a = ws;  ws += S_OP2;
  p.outp2b = ws;  ws += S_OP2;
  p.u1s    = ws;  ws += S_U1S;
  p.dm0    = ws;  ws += S_OUT0;
  p.dm1    = ws;  ws += S_DM1;
  p.dmp1   = ws;  ws += S_OP1;
  p.dm2    = ws;  ws += S_OP1;
  p.dmp2   = ws;  ws += S_OP2;
  p.dmh1   = ws;  ws += S_OH1;
  p.dmh2   = ws;  ws += (size_t)NB*11;
  p.dmz    = p.dm0;
  p.dmz_n4 = (int)((S_OUT0 + S_DM1 + S_OP1 + S_OP1 + S_OP2 + S_OH1 + (size_t)NB*11) / 4);

  // prep on primary, then fork sB/sC into the capture DAG
  k_prep<<<dim3(1024), dim3(NTHR), 0, stream>>>(p);
  hipEventRecord(evFork, stream);
  hipStreamWaitEvent(sB, evFork, 0);
  hipStreamWaitEvent(sC, evFork, 0);

  for(int t=0; t<NT; t++){
    float* out0w  = (t&1) ? p.out0b  : p.out0a;
    float* outp2w = (t&1) ? p.outp2b : p.outp2a;
    const float* xt = p.xb + (size_t)t*NB*2*32*32;

    // --- stream C: conv0(t) ---
    if(t >= 2) hipStreamWaitEvent(sC, evA1[t-2], 0);   // conv1(t-2) done reading out0 buffer
    k_conv<2,64,32,8,2,8,false,2><<<dim3(576), dim3(NTHR), 0, sC>>>(
        xt, p.w0t, p.b0, p.dm0, out0w, nullptr, nullptr);
    hipEventRecord(evC[t], sC);

    // --- stream A: conv1(t) ---
    hipStreamWaitEvent(stream, evC[t], 0);             // out0(t) ready
    k_conv<64,128,32,8,2,8,true,64><<<dim3(1152), dim3(NTHR), 0, stream>>>(
        out0w, p.w1t, p.b1, p.dm1, nullptr, p.dmp1, p.outp1);
    hipEventRecord(evA1[t], stream);

    // --- stream A: conv2(t) ---
    if(t >= 2) hipStreamWaitEvent(stream, evB[t-2], 0); // fc1(t-2) done reading outp2 buffer
    k_conv<128,128,16,8,1,16,true,64><<<dim3(576), dim3(NTHR), 0, stream>>>(
        p.outp1, p.w2t, p.b2, p.dm2, nullptr, p.dmp2, outp2w);
    hipEventRecord(evA2[t], stream);

    // --- stream B: fc1(t) + fc2(t) ---
    hipStreamWaitEvent(sB, evA2[t], 0);                // outp2(t) ready
    k_fc1<<<dim3(256), dim3(NTHR), 0, sB>>>(outp2w, p.Wf1, p.u1s);
    k_fc2<<<dim3(36), dim3(NTHR), 0, sB>>>(p.u1s, p.bf1, p.Wf2, p.bf2,
                                           p.dmh1, p.dmh2, p.acc);
    hipEventRecord(evB[t], sB);
  }

  // join both side streams back to primary
  hipStreamWaitEvent(stream, evB[NT-1], 0);
  hipStreamWaitEvent(stream, evC[NT-1], 0);
}

// Round 8
// 13453.287 us; speedup vs baseline: 1.1866x; 1.1866x over previous
//
#include <hip/hip_runtime.h>

#define NB 36
#define NT 60

// ---------------- prep: zero states+halos, binarize into padded xb, transpose weights ----------------
struct Params {
  const float *data;
  const float *W0, *b0, *W1, *b1, *W2, *b2, *Wf1, *bf1, *Wf2, *bf2;
  float *xb, *w0t, *w1t, *w2t;
  float *out0, *outp1, *outp2, *u1s;
  float *dm0, *dm1, *dmp1, *dm2, *dmp2, *dmh1, *dmh2;
  float *acc;
  float *zbase; int zn4;
};

__global__ void __launch_bounds__(256) k_prep(Params p){
  int gt  = blockIdx.x*256 + threadIdx.x;
  int STR = gridDim.x*256;
  if(gt < NB*11) p.acc[gt] = 0.f;
  for(int i=gt; i<p.zn4; i+=STR) ((float4*)p.zbase)[i] = make_float4(0.f,0.f,0.f,0.f);
  // xb: [t][b*2+c][34][34], halo = 0
  const int PLANE = 34*34;
  for(int i=gt; i<NT*NB*2*PLANE; i+=STR){
    int t   = i / (NB*2*PLANE);
    int rem = i % (NB*2*PLANE);
    int bc  = rem / PLANE;
    int pix = rem % PLANE;
    int ph = pix/34, pw = pix%34;
    float v = 0.f;
    if(ph>=1 && ph<=32 && pw>=1 && pw<=32){
      float d = p.data[((size_t)bc*1024 + (ph-1)*32 + (pw-1))*NT + t];
      v = (d > 1.0f) ? 1.0f : 0.0f;
    }
    p.xb[i] = v;
  }
  for(int i=gt; i<2*9*64; i+=STR){
    int co=i%64, rr=i/64; p.w0t[i] = p.W0[(co*2 + rr/9)*9 + rr%9];
  }
  for(int i=gt; i<64*9*128; i+=STR){
    int co=i%128, rr=i/128; p.w1t[i] = p.W1[(co*64 + rr/9)*9 + rr%9];
  }
  for(int i=gt; i<128*9*128; i+=STR){
    int co=i%128, rr=i/128; p.w2t[i] = p.W2[(co*128 + rr/9)*9 + rr%9];
  }
}

// ---------------- fused conv3x3 + LIAF (+ optional avgpool2 + LIAF) ----------------
// Input x is halo-padded (stride HW+2, interior at [1..HW][1..HW]) -> NO bounds
// checks in the inner loop. Weights staged in LDS in CS-cin chunks, read as
// float4 broadcasts. Thread: w=tid%HW, ty=tid/HW, PX rows x CO couts.
// OPAD: out/dm padded (conv0).  POOL: dm packed, pooled out padded iff PPAD.
template<int Cin,int Cout,int HW,int CO,int PX,int TY,int POOL,int OPAD,int PPAD,int CS>
__global__ void __launch_bounds__(HW*TY)
k_conv(const float* __restrict__ x, const float* __restrict__ wt,
       const float* __restrict__ bias, float* __restrict__ dm,
       float* __restrict__ out, float* __restrict__ dmp, float* __restrict__ outp)
{
  const int NCOG = Cout/CO;
  const int TH   = PX*TY;
  const int NHG  = HW/TH;
  const int NH4  = CO/4;
  const int NTHL = HW*TY;
  const int PIN  = HW+2;
  int tile = blockIdx.x;
  int tid  = threadIdx.x;
  int cog = tile % NCOG;
  int hg  = (tile/NCOG) % NHG;
  int b   = tile/(NCOG*NHG);
  int w   = tid % HW;
  int ty  = tid / HW;
  int h0  = hg*TH + ty*PX;

  __shared__ __align__(16) float wl[CS*9*CO];

  float accs[PX][CO];
  #pragma unroll
  for(int p=0;p<PX;p++)
    #pragma unroll
    for(int c=0;c<CO;c++) accs[p][c]=0.f;

  for(int cs=0; cs<Cin; cs+=CS){
    __syncthreads();
    for(int j=tid; j<CS*9*CO; j+=NTHL){
      int c  = j % CO;
      int rr = j / CO;
      wl[j] = wt[(cs*9 + rr)*Cout + cog*CO + c];
    }
    __syncthreads();

    for(int lc=0; lc<CS; lc++){
      const float* xc = x + ((size_t)b*Cin + cs + lc)*PIN*PIN;
      float xmv[PX+2], x0v[PX+2], xpv[PX+2];
      #pragma unroll
      for(int r=0;r<PX+2;r++){
        const float* xr = xc + (size_t)(h0+r)*PIN + w;   // padded: no bounds checks
        xmv[r] = xr[0];
        x0v[r] = xr[1];
        xpv[r] = xr[2];
      }
      const float4* w4 = (const float4*)(wl + lc*9*CO);
      #pragma unroll
      for(int dh=0;dh<3;dh++){
        float4 wa[NH4], wb[NH4], wc[NH4];
        #pragma unroll
        for(int g=0;g<NH4;g++){
          wa[g] = w4[(dh*3+0)*NH4+g];
          wb[g] = w4[(dh*3+1)*NH4+g];
          wc[g] = w4[(dh*3+2)*NH4+g];
        }
        #pragma unroll
        for(int g=0;g<NH4;g++){
          const float* A  = (const float*)&wa[g];
          const float* Bp = (const float*)&wb[g];
          const float* Cp = (const float*)&wc[g];
          #pragma unroll
          for(int cc=0;cc<4;cc++){
            #pragma unroll
            for(int px=0;px<PX;px++){
              int r = dh+px;
              accs[px][g*4+cc] += A[cc]*xmv[r] + Bp[cc]*x0v[r] + Cp[cc]*xpv[r];
            }
          }
        }
      }
    }
  }

  int co0 = cog*CO;
  #pragma unroll
  for(int co=0; co<CO; co++){
    float bsv = bias[co0+co];
    if constexpr(!POOL){
      const int OS = HW + 2*OPAD;
      size_t plane = (size_t)(b*Cout + co0+co)*OS*OS;
      #pragma unroll
      for(int px=0; px<PX; px++){
        size_t idx = plane + (size_t)(h0+px+OPAD)*OS + w + OPAD;
        float mem = dm[idx] + accs[px][co] + bsv;
        out[idx] = mem > 0.f ? mem : 0.f;
        dm[idx]  = (mem > 0.5f) ? 0.f : 0.3f*mem;
      }
    } else {
      // conv LIAF at full res (dm packed), then 2x2 pool + pool LIAF
      size_t dplane = (size_t)(b*Cout + co0+co)*HW*HW;
      float vs[PX/2];
      #pragma unroll
      for(int pr=0;pr<PX/2;pr++) vs[pr]=0.f;
      #pragma unroll
      for(int px=0; px<PX; px++){
        size_t idx = dplane + (size_t)(h0+px)*HW + w;
        float mem = dm[idx] + accs[px][co] + bsv;
        float o = mem > 0.f ? mem : 0.f;
        dm[idx] = (mem > 0.5f) ? 0.f : 0.3f*mem;
        vs[px>>1] += o;
      }
      const int PS = HW/2 + 2*PPAD;
      size_t pplane = (size_t)(b*Cout + co0+co)*PS*PS;
      #pragma unroll
      for(int pr=0; pr<PX/2; pr++){
        float s = vs[pr];
        s += __shfl_xor(s, 1, 64);
        if((w&1)==0){
          int ph = (h0>>1)+pr, pw = w>>1;
          size_t pidx = pplane + (size_t)(ph+PPAD)*PS + pw + PPAD;
          float pm = dmp[pidx] + s*0.25f;
          outp[pidx] = pm > 0.f ? pm : 0.f;
          dmp[pidx]  = (pm > 0.5f) ? 0.f : 0.3f*pm;
        }
      }
    }
  }
}

// ---------------- FC1 partial GEMM -> 32 slices ----------------
__global__ void __launch_bounds__(256)
k_fc1(const float* __restrict__ X, const float* __restrict__ Wf,
      float* __restrict__ u1s){
  __shared__ __align__(16) float lds[4896];
  float* Wl = lds;
  float* Xl = lds + 32*68;
  const int tid = threadIdx.x;
  int ot = blockIdx.x & 7, ks = blockIdx.x >> 3;
  int o0 = ot*32, k0 = ks*256;
  int w_id = tid >> 6, lane = tid & 63;
  int o_l = lane & 7, bg = lane >> 3;
  float acc[4][5];
  #pragma unroll
  for(int i=0;i<4;i++)
    #pragma unroll
    for(int j=0;j<5;j++) acc[i][j]=0.f;

  for(int c=0; c<4; c++){
    int kb = k0 + c*64;
    __syncthreads();
    for(int idx=tid; idx<512; idx+=256){
      int r = idx >> 4, j = idx & 15;
      *(float4*)&Wl[r*68 + j*4] = *(const float4*)&Wf[(size_t)(o0+r)*8192 + kb + j*4];
    }
    for(int idx=tid; idx<640; idx+=256){
      int r = idx >> 4, j = idx & 15;
      float4 v = make_float4(0.f,0.f,0.f,0.f);
      if(r < NB) v = *(const float4*)&X[(size_t)r*8192 + kb + j*4];
      *(float4*)&Xl[r*68 + j*4] = v;
    }
    __syncthreads();
    #pragma unroll
    for(int c4=0; c4<4; c4++){
      int g = w_id*4 + c4;
      float4 wv[4], xv[5];
      #pragma unroll
      for(int oi=0;oi<4;oi++) wv[oi] = *(const float4*)&Wl[(o_l+8*oi)*68 + g*4];
      #pragma unroll
      for(int bi=0;bi<5;bi++) xv[bi] = *(const float4*)&Xl[(bg*5+bi)*68 + g*4];
      #pragma unroll
      for(int oi=0;oi<4;oi++)
        #pragma unroll
        for(int bi=0;bi<5;bi++)
          acc[oi][bi] += wv[oi].x*xv[bi].x + wv[oi].y*xv[bi].y
                       + wv[oi].z*xv[bi].z + wv[oi].w*xv[bi].w;
    }
  }
  __syncthreads();
  if(w_id > 0){
    float* r = lds + ((w_id-1)*64 + lane)*20;
    #pragma unroll
    for(int oi=0;oi<4;oi++)
      #pragma unroll
      for(int bi=0;bi<5;bi++) r[oi*5+bi] = acc[oi][bi];
  }
  __syncthreads();
  if(w_id == 0){
    #pragma unroll
    for(int wv=0;wv<3;wv++){
      float* r = lds + (wv*64 + lane)*20;
      #pragma unroll
      for(int oi=0;oi<4;oi++)
        #pragma unroll
        for(int bi=0;bi<5;bi++) acc[oi][bi] += r[oi*5+bi];
    }
    #pragma unroll
    for(int bi=0;bi<5;bi++){
      int b = bg*5 + bi;
      if(b < NB){
        #pragma unroll
        for(int oi=0;oi<4;oi++)
          u1s[((size_t)ks*NB + b)*256 + o0 + o_l + 8*oi] = acc[oi][bi];
      }
    }
  }
}

// ---------------- FC1-reduce + LIAF + FC2 + LIAF + accumulate ----------------
__global__ void __launch_bounds__(256)
k_fc2(const float* __restrict__ u1s, const float* __restrict__ bf1,
      const float* __restrict__ Wf2, const float* __restrict__ bf2,
      float* __restrict__ dmh1, float* __restrict__ dmh2, float* __restrict__ acc){
  __shared__ float xs[256];
  int b = blockIdx.x;
  int o = threadIdx.x;
  float u = bf1[o];
  const float* p = u1s + (size_t)b*256 + o;
  #pragma unroll
  for(int s=0;s<32;s++) u += p[(size_t)s*NB*256];
  int idx = b*256 + o;
  float mem = dmh1[idx] + u;
  float xo = mem > 0.f ? mem : 0.f;
  dmh1[idx] = (mem > 0.5f) ? 0.f : 0.3f*mem;
  xs[o] = xo;
  __syncthreads();
  int w_id = o >> 6, lane = o & 63;
  for(int oo=w_id; oo<11; oo+=4){
    const float* wr = Wf2 + oo*256;
    float s = xs[lane]*wr[lane] + xs[lane+64]*wr[lane+64]
            + xs[lane+128]*wr[lane+128] + xs[lane+192]*wr[lane+192];
    #pragma unroll
    for(int off=32; off>0; off>>=1) s += __shfl_down(s, off, 64);
    if(lane==0){
      int i2 = b*11 + oo;
      float m2 = dmh2[i2] + s + bf2[oo];
      float ov = m2 > 0.f ? m2 : 0.f;
      dmh2[i2] = (m2 > 0.5f) ? 0.f : 0.3f*m2;
      acc[i2] += ov * (1.0f/60.0f);
    }
  }
}

// ==================== launch (single stream, serial) ====================
extern "C" void kernel_launch(void* const* d_in, const int* in_sizes, int n_in,
                              void* d_out, int out_size, void* d_ws, size_t ws_size,
                              hipStream_t stream) {
  Params p;
  p.data = (const float*)d_in[0];
  p.W0  = (const float*)d_in[2];  p.b0  = (const float*)d_in[3];
  p.W1  = (const float*)d_in[4];  p.b1  = (const float*)d_in[5];
  p.W2  = (const float*)d_in[6];  p.b2  = (const float*)d_in[7];
  p.Wf1 = (const float*)d_in[8];  p.bf1 = (const float*)d_in[9];
  p.Wf2 = (const float*)d_in[10]; p.bf2 = (const float*)d_in[11];
  p.acc = (float*)d_out;

  float* ws = (float*)d_ws;
  const size_t S_XB    = (size_t)NT*NB*2*34*34;   // padded
  const size_t S_W0T   = 2*9*64;
  const size_t S_W1T   = 64*9*128;
  const size_t S_W2T   = 128*9*128;
  const size_t S_OUT0  = (size_t)NB*64*34*34;     // padded
  const size_t S_OP1   = (size_t)NB*128*18*18;    // padded
  const size_t S_OP2   = (size_t)NB*128*8*8;      // packed
  const size_t S_U1S   = (size_t)32*NB*256;
  const size_t S_DM0   = S_OUT0;                  // padded (shares indexing)
  const size_t S_DM1   = (size_t)NB*128*32*32;    // packed
  const size_t S_DMP1  = S_OP1;                   // padded
  const size_t S_DM2   = (size_t)NB*128*16*16;    // packed
  const size_t S_DMP2  = S_OP2;                   // packed
  const size_t S_OH1   = (size_t)NB*256;

  p.xb    = ws;  ws += S_XB;
  p.w0t   = ws;  ws += S_W0T;
  p.w1t   = ws;  ws += S_W1T;
  p.w2t   = ws;  ws += S_W2T;
  p.zbase = ws;                       // zero everything from here down
  p.out0  = ws;  ws += S_OUT0;
  p.outp1 = ws;  ws += S_OP1;
  p.outp2 = ws;  ws += S_OP2;
  p.u1s   = ws;  ws += S_U1S;
  p.dm0   = ws;  ws += S_DM0;
  p.dm1   = ws;  ws += S_DM1;
  p.dmp1  = ws;  ws += S_DMP1;
  p.dm2   = ws;  ws += S_DM2;
  p.dmp2  = ws;  ws += S_DMP2;
  p.dmh1  = ws;  ws += S_OH1;
  p.dmh2  = ws;  ws += (size_t)NB*11;
  p.zn4   = (int)((ws - p.zbase) / 4);

  k_prep<<<dim3(1024), dim3(256), 0, stream>>>(p);
  for(int t=0; t<NT; t++){
    const float* xt = p.xb + (size_t)t*NB*2*34*34;
    // conv0: 2->64 @32x32, PX=4, 256thr, out0/dm0 padded  (288 blocks)
    k_conv<2,64,32,8,4,8,0,1,0,2><<<dim3(288), dim3(256), 0, stream>>>(
        xt, p.w0t, p.b0, p.dm0, p.out0, nullptr, nullptr);
    // conv1+pool1: 64->128 @32x32, PX=4, 128thr, pooled out padded (1152 blocks)
    k_conv<64,128,32,8,4,4,1,0,1,64><<<dim3(1152), dim3(128), 0, stream>>>(
        p.out0, p.w1t, p.b1, p.dm1, nullptr, p.dmp1, p.outp1);
    // conv2+pool2: 128->128 @16x16, PX=2, CO=4, 64thr, pooled out packed (2304 blocks)
    k_conv<128,128,16,4,2,4,1,0,0,64><<<dim3(2304), dim3(64), 0, stream>>>(
        p.outp1, p.w2t, p.b2, p.dm2, nullptr, p.dmp2, p.outp2);
    // fc1 -> 32 slices (256 blocks)
    k_fc1<<<dim3(256), dim3(256), 0, stream>>>(p.outp2, p.Wf1, p.u1s);
    // fc1-reduce + LIAF + fc2 + LIAF + accumulate (36 blocks)
    k_fc2<<<dim3(36), dim3(256), 0, stream>>>(p.u1s, p.bf1, p.Wf2, p.bf2,
                                              p.dmh1, p.dmh2, p.acc);
  }
}

// Round 9
// 12636.756 us; speedup vs baseline: 1.2632x; 1.0646x over previous
//
#include <hip/hip_runtime.h>

#define NB 36
#define NT 60

// ---------------- prep: zero states+halos, binarize into padded xb, transpose weights ----------------
struct Params {
  const float *data;
  const float *W0, *b0, *W1, *b1, *W2, *b2, *Wf1, *bf1, *Wf2, *bf2;
  float *xb, *w0t, *w1t, *w2t;
  float *out0, *outp1, *outp2, *u1s;
  float *dm0, *dm1, *dmp1, *dm2, *dmp2, *dmh1, *dmh2;
  float *acc;
  float *zbase; int zn4;
};

__global__ void __launch_bounds__(256) k_prep(Params p){
  int gt  = blockIdx.x*256 + threadIdx.x;
  int STR = gridDim.x*256;
  if(gt < NB*11) p.acc[gt] = 0.f;
  for(int i=gt; i<p.zn4; i+=STR) ((float4*)p.zbase)[i] = make_float4(0.f,0.f,0.f,0.f);
  // xb: [t][b*2+c][34][34], halo = 0
  const int PLANE = 34*34;
  for(int i=gt; i<NT*NB*2*PLANE; i+=STR){
    int t   = i / (NB*2*PLANE);
    int rem = i % (NB*2*PLANE);
    int bc  = rem / PLANE;
    int pix = rem % PLANE;
    int ph = pix/34, pw = pix%34;
    float v = 0.f;
    if(ph>=1 && ph<=32 && pw>=1 && pw<=32){
      float d = p.data[((size_t)bc*1024 + (ph-1)*32 + (pw-1))*NT + t];
      v = (d > 1.0f) ? 1.0f : 0.0f;
    }
    p.xb[i] = v;
  }
  for(int i=gt; i<2*9*64; i+=STR){
    int co=i%64, rr=i/64; p.w0t[i] = p.W0[(co*2 + rr/9)*9 + rr%9];
  }
  for(int i=gt; i<64*9*128; i+=STR){
    int co=i%128, rr=i/128; p.w1t[i] = p.W1[(co*64 + rr/9)*9 + rr%9];
  }
  for(int i=gt; i<128*9*128; i+=STR){
    int co=i%128, rr=i/128; p.w2t[i] = p.W2[(co*128 + rr/9)*9 + rr%9];
  }
}

// ---------------- fused conv3x3 + LIAF (+ optional avgpool2 + LIAF) ----------------
// Halo-padded input (stride HW+2) -> no bounds checks. Weights staged in LDS,
// read as float4 broadcasts. SW-PIPELINED: each lc-iteration prefetches the
// next cin's input rows into a second register set before the current FMAs,
// hiding global-load latency behind the 576-cyc FMA block.
template<int Cin,int Cout,int HW,int CO,int PX,int TY,int POOL,int OPAD,int PPAD,int CS>
__global__ void __launch_bounds__(HW*TY)
k_conv(const float* __restrict__ x, const float* __restrict__ wt,
       const float* __restrict__ bias, float* __restrict__ dm,
       float* __restrict__ out, float* __restrict__ dmp, float* __restrict__ outp)
{
  const int NCOG = Cout/CO;
  const int TH   = PX*TY;
  const int NHG  = HW/TH;
  const int NH4  = CO/4;
  const int NTHL = HW*TY;
  const int PIN  = HW+2;
  int tile = blockIdx.x;
  int tid  = threadIdx.x;
  int cog = tile % NCOG;
  int hg  = (tile/NCOG) % NHG;
  int b   = tile/(NCOG*NHG);
  int w   = tid % HW;
  int ty  = tid / HW;
  int h0  = hg*TH + ty*PX;

  __shared__ __align__(16) float wl[CS*9*CO];

  float accs[PX][CO];
  #pragma unroll
  for(int p=0;p<PX;p++)
    #pragma unroll
    for(int c=0;c<CO;c++) accs[p][c]=0.f;

  for(int cs=0; cs<Cin; cs+=CS){
    __syncthreads();
    for(int j=tid; j<CS*9*CO; j+=NTHL){
      int c  = j % CO;
      int rr = j / CO;
      wl[j] = wt[(cs*9 + rr)*Cout + cog*CO + c];
    }
    __syncthreads();

    // preload lc=0 input rows
    float xmv[PX+2], x0v[PX+2], xpv[PX+2];
    {
      const float* xc = x + ((size_t)b*Cin + cs)*PIN*PIN;
      #pragma unroll
      for(int r=0;r<PX+2;r++){
        const float* xr = xc + (size_t)(h0+r)*PIN + w;
        xmv[r]=xr[0]; x0v[r]=xr[1]; xpv[r]=xr[2];
      }
    }

    for(int lc=0; lc<CS; lc++){
      // prefetch next cin's rows (last iter: reload current -> branch-free)
      int lcn = (lc+1 < CS) ? lc+1 : lc;
      float nmv[PX+2], n0v[PX+2], npv[PX+2];
      {
        const float* xc = x + ((size_t)b*Cin + cs + lcn)*PIN*PIN;
        #pragma unroll
        for(int r=0;r<PX+2;r++){
          const float* xr = xc + (size_t)(h0+r)*PIN + w;
          nmv[r]=xr[0]; n0v[r]=xr[1]; npv[r]=xr[2];
        }
      }
      const float4* w4 = (const float4*)(wl + lc*9*CO);
      #pragma unroll
      for(int dh=0;dh<3;dh++){
        float4 wa[NH4], wb[NH4], wc[NH4];
        #pragma unroll
        for(int g=0;g<NH4;g++){
          wa[g] = w4[(dh*3+0)*NH4+g];
          wb[g] = w4[(dh*3+1)*NH4+g];
          wc[g] = w4[(dh*3+2)*NH4+g];
        }
        #pragma unroll
        for(int g=0;g<NH4;g++){
          const float* A  = (const float*)&wa[g];
          const float* Bp = (const float*)&wb[g];
          const float* Cp = (const float*)&wc[g];
          #pragma unroll
          for(int cc=0;cc<4;cc++){
            #pragma unroll
            for(int px=0;px<PX;px++){
              int r = dh+px;
              accs[px][g*4+cc] += A[cc]*xmv[r] + Bp[cc]*x0v[r] + Cp[cc]*xpv[r];
            }
          }
        }
      }
      // rotate prefetched registers in
      #pragma unroll
      for(int r=0;r<PX+2;r++){ xmv[r]=nmv[r]; x0v[r]=n0v[r]; xpv[r]=npv[r]; }
    }
  }

  int co0 = cog*CO;
  #pragma unroll
  for(int co=0; co<CO; co++){
    float bsv = bias[co0+co];
    if constexpr(!POOL){
      const int OS = HW + 2*OPAD;
      size_t plane = (size_t)(b*Cout + co0+co)*OS*OS;
      #pragma unroll
      for(int px=0; px<PX; px++){
        size_t idx = plane + (size_t)(h0+px+OPAD)*OS + w + OPAD;
        float mem = dm[idx] + accs[px][co] + bsv;
        out[idx] = mem > 0.f ? mem : 0.f;
        dm[idx]  = (mem > 0.5f) ? 0.f : 0.3f*mem;
      }
    } else {
      size_t dplane = (size_t)(b*Cout + co0+co)*HW*HW;
      float vs[PX/2];
      #pragma unroll
      for(int pr=0;pr<PX/2;pr++) vs[pr]=0.f;
      #pragma unroll
      for(int px=0; px<PX; px++){
        size_t idx = dplane + (size_t)(h0+px)*HW + w;
        float mem = dm[idx] + accs[px][co] + bsv;
        float o = mem > 0.f ? mem : 0.f;
        dm[idx] = (mem > 0.5f) ? 0.f : 0.3f*mem;
        vs[px>>1] += o;
      }
      const int PS = HW/2 + 2*PPAD;
      size_t pplane = (size_t)(b*Cout + co0+co)*PS*PS;
      #pragma unroll
      for(int pr=0; pr<PX/2; pr++){
        float s = vs[pr];
        s += __shfl_xor(s, 1, 64);
        if((w&1)==0){
          int ph = (h0>>1)+pr, pw = w>>1;
          size_t pidx = pplane + (size_t)(ph+PPAD)*PS + pw + PPAD;
          float pm = dmp[pidx] + s*0.25f;
          outp[pidx] = pm > 0.f ? pm : 0.f;
          dmp[pidx]  = (pm > 0.5f) ? 0.f : 0.3f*pm;
        }
      }
    }
  }
}

// ---------------- FC1 partial GEMM -> 32 slices ----------------
__global__ void __launch_bounds__(256)
k_fc1(const float* __restrict__ X, const float* __restrict__ Wf,
      float* __restrict__ u1s){
  __shared__ __align__(16) float lds[4896];
  float* Wl = lds;
  float* Xl = lds + 32*68;
  const int tid = threadIdx.x;
  int ot = blockIdx.x & 7, ks = blockIdx.x >> 3;
  int o0 = ot*32, k0 = ks*256;
  int w_id = tid >> 6, lane = tid & 63;
  int o_l = lane & 7, bg = lane >> 3;
  float acc[4][5];
  #pragma unroll
  for(int i=0;i<4;i++)
    #pragma unroll
    for(int j=0;j<5;j++) acc[i][j]=0.f;

  for(int c=0; c<4; c++){
    int kb = k0 + c*64;
    __syncthreads();
    for(int idx=tid; idx<512; idx+=256){
      int r = idx >> 4, j = idx & 15;
      *(float4*)&Wl[r*68 + j*4] = *(const float4*)&Wf[(size_t)(o0+r)*8192 + kb + j*4];
    }
    for(int idx=tid; idx<640; idx+=256){
      int r = idx >> 4, j = idx & 15;
      float4 v = make_float4(0.f,0.f,0.f,0.f);
      if(r < NB) v = *(const float4*)&X[(size_t)r*8192 + kb + j*4];
      *(float4*)&Xl[r*68 + j*4] = v;
    }
    __syncthreads();
    #pragma unroll
    for(int c4=0; c4<4; c4++){
      int g = w_id*4 + c4;
      float4 wv[4], xv[5];
      #pragma unroll
      for(int oi=0;oi<4;oi++) wv[oi] = *(const float4*)&Wl[(o_l+8*oi)*68 + g*4];
      #pragma unroll
      for(int bi=0;bi<5;bi++) xv[bi] = *(const float4*)&Xl[(bg*5+bi)*68 + g*4];
      #pragma unroll
      for(int oi=0;oi<4;oi++)
        #pragma unroll
        for(int bi=0;bi<5;bi++)
          acc[oi][bi] += wv[oi].x*xv[bi].x + wv[oi].y*xv[bi].y
                       + wv[oi].z*xv[bi].z + wv[oi].w*xv[bi].w;
    }
  }
  __syncthreads();
  if(w_id > 0){
    float* r = lds + ((w_id-1)*64 + lane)*20;
    #pragma unroll
    for(int oi=0;oi<4;oi++)
      #pragma unroll
      for(int bi=0;bi<5;bi++) r[oi*5+bi] = acc[oi][bi];
  }
  __syncthreads();
  if(w_id == 0){
    #pragma unroll
    for(int wv=0;wv<3;wv++){
      float* r = lds + (wv*64 + lane)*20;
      #pragma unroll
      for(int oi=0;oi<4;oi++)
        #pragma unroll
        for(int bi=0;bi<5;bi++) acc[oi][bi] += r[oi*5+bi];
    }
    #pragma unroll
    for(int bi=0;bi<5;bi++){
      int b = bg*5 + bi;
      if(b < NB){
        #pragma unroll
        for(int oi=0;oi<4;oi++)
          u1s[((size_t)ks*NB + b)*256 + o0 + o_l + 8*oi] = acc[oi][bi];
      }
    }
  }
}

// ---------------- FC1-reduce + LIAF + FC2 + LIAF + accumulate ----------------
__global__ void __launch_bounds__(256)
k_fc2(const float* __restrict__ u1s, const float* __restrict__ bf1,
      const float* __restrict__ Wf2, const float* __restrict__ bf2,
      float* __restrict__ dmh1, float* __restrict__ dmh2, float* __restrict__ acc){
  __shared__ float xs[256];
  int b = blockIdx.x;
  int o = threadIdx.x;
  float u = bf1[o];
  const float* p = u1s + (size_t)b*256 + o;
  #pragma unroll
  for(int s=0;s<32;s++) u += p[(size_t)s*NB*256];
  int idx = b*256 + o;
  float mem = dmh1[idx] + u;
  float xo = mem > 0.f ? mem : 0.f;
  dmh1[idx] = (mem > 0.5f) ? 0.f : 0.3f*mem;
  xs[o] = xo;
  __syncthreads();
  int w_id = o >> 6, lane = o & 63;
  for(int oo=w_id; oo<11; oo+=4){
    const float* wr = Wf2 + oo*256;
    float s = xs[lane]*wr[lane] + xs[lane+64]*wr[lane+64]
            + xs[lane+128]*wr[lane+128] + xs[lane+192]*wr[lane+192];
    #pragma unroll
    for(int off=32; off>0; off>>=1) s += __shfl_down(s, off, 64);
    if(lane==0){
      int i2 = b*11 + oo;
      float m2 = dmh2[i2] + s + bf2[oo];
      float ov = m2 > 0.f ? m2 : 0.f;
      dmh2[i2] = (m2 > 0.5f) ? 0.f : 0.3f*m2;
      acc[i2] += ov * (1.0f/60.0f);
    }
  }
}

// ==================== launch (single stream, serial) ====================
extern "C" void kernel_launch(void* const* d_in, const int* in_sizes, int n_in,
                              void* d_out, int out_size, void* d_ws, size_t ws_size,
                              hipStream_t stream) {
  Params p;
  p.data = (const float*)d_in[0];
  p.W0  = (const float*)d_in[2];  p.b0  = (const float*)d_in[3];
  p.W1  = (const float*)d_in[4];  p.b1  = (const float*)d_in[5];
  p.W2  = (const float*)d_in[6];  p.b2  = (const float*)d_in[7];
  p.Wf1 = (const float*)d_in[8];  p.bf1 = (const float*)d_in[9];
  p.Wf2 = (const float*)d_in[10]; p.bf2 = (const float*)d_in[11];
  p.acc = (float*)d_out;

  float* ws = (float*)d_ws;
  const size_t S_XB    = (size_t)NT*NB*2*34*34;   // padded
  const size_t S_W0T   = 2*9*64;
  const size_t S_W1T   = 64*9*128;
  const size_t S_W2T   = 128*9*128;
  const size_t S_OUT0  = (size_t)NB*64*34*34;     // padded
  const size_t S_OP1   = (size_t)NB*128*18*18;    // padded
  const size_t S_OP2   = (size_t)NB*128*8*8;      // packed
  const size_t S_U1S   = (size_t)32*NB*256;
  const size_t S_DM0   = S_OUT0;                  // padded
  const size_t S_DM1   = (size_t)NB*128*32*32;    // packed
  const size_t S_DMP1  = S_OP1;                   // padded
  const size_t S_DM2   = (size_t)NB*128*16*16;    // packed
  const size_t S_DMP2  = S_OP2;                   // packed
  const size_t S_OH1   = (size_t)NB*256;

  p.xb    = ws;  ws += S_XB;
  p.w0t   = ws;  ws += S_W0T;
  p.w1t   = ws;  ws += S_W1T;
  p.w2t   = ws;  ws += S_W2T;
  p.zbase = ws;
  p.out0  = ws;  ws += S_OUT0;
  p.outp1 = ws;  ws += S_OP1;
  p.outp2 = ws;  ws += S_OP2;
  p.u1s   = ws;  ws += S_U1S;
  p.dm0   = ws;  ws += S_DM0;
  p.dm1   = ws;  ws += S_DM1;
  p.dmp1  = ws;  ws += S_DMP1;
  p.dm2   = ws;  ws += S_DM2;
  p.dmp2  = ws;  ws += S_DMP2;
  p.dmh1  = ws;  ws += S_OH1;
  p.dmh2  = ws;  ws += (size_t)NB*11;
  p.zn4   = (int)((ws - p.zbase) / 4);

  k_prep<<<dim3(1024), dim3(256), 0, stream>>>(p);
  for(int t=0; t<NT; t++){
    const float* xt = p.xb + (size_t)t*NB*2*34*34;
    // conv0: 2->64 @32x32, PX=4, 256thr, out0/dm0 padded  (288 blocks)
    k_conv<2,64,32,8,4,8,0,1,0,2><<<dim3(288), dim3(256), 0, stream>>>(
        xt, p.w0t, p.b0, p.dm0, p.out0, nullptr, nullptr);
    // conv1+pool1: 64->128 @32x32, PX=4, 128thr, pooled out padded (1152 blocks)
    k_conv<64,128,32,8,4,4,1,0,1,64><<<dim3(1152), dim3(128), 0, stream>>>(
        p.out0, p.w1t, p.b1, p.dm1, nullptr, p.dmp1, p.outp1);
    // conv2+pool2: 128->128 @16x16, PX=2, CO=4, 64thr, pooled out packed (2304 blocks)
    k_conv<128,128,16,4,2,4,1,0,0,64><<<dim3(2304), dim3(64), 0, stream>>>(
        p.outp1, p.w2t, p.b2, p.dm2, nullptr, p.dmp2, p.outp2);
    // fc1 -> 32 slices (256 blocks)
    k_fc1<<<dim3(256), dim3(256), 0, stream>>>(p.outp2, p.Wf1, p.u1s);
    // fc1-reduce + LIAF + fc2 + LIAF + accumulate (36 blocks)
    k_fc2<<<dim3(36), dim3(256), 0, stream>>>(p.u1s, p.bf1, p.Wf2, p.bf2,
                                              p.dmh1, p.dmh2, p.acc);
  }
}